// Round 10
// baseline (222.221 us; speedup 1.0000x reference)
//
#include <hip/hip_runtime.h>

#define DSZ 96
#define CIN 16
#define NF  16

typedef __attribute__((ext_vector_type(8))) short short8;   // 8 bf16
typedef __attribute__((ext_vector_type(4))) float f32x4;    // MFMA C/D

union I4S8 { int4 i; short8 s; };

// ---------------- prepass: pack w into B-fragment layout (R6-validated) ----
// k = ((l>>4)&1)*8 + j ; tap = 2t + (l>>5) ; tap 27 -> zeros.
__global__ void pack_w(const float* __restrict__ w, short* __restrict__ wpack) {
  const int t = threadIdx.x >> 6;   // 0..13
  const int l = threadIdx.x & 63;
  const int tap = 2 * t + (l >> 5);
  const int cib = ((l >> 4) & 1) * 8;
  const int f = l & 15;
  short v[8];
#pragma unroll
  for (int j = 0; j < 8; ++j) {
    float x = (tap <= 26) ? w[(tap * 16 + cib + j) * 16 + f] : 0.0f;
    unsigned u = __float_as_uint(x);
    u = (u + 0x7FFFu + ((u >> 16) & 1u)) >> 16;  // RNE to bf16
    v[j] = (short)u;
  }
  short8 s;
#pragma unroll
  for (int j = 0; j < 8; ++j) s[j] = v[j];
  reinterpret_cast<short8*>(wpack)[t * 64 + l] = s;
}

// ---------------- main: persistent z-column, T14 slab pipeline ----------------
// Block = 512 threads (8 waves) owns 8x8 xy x 48 z (3 slabs of 16).
// Per slab: issue iv loads + next-slab global loads (held in regs), compute
// current slab from LDS (R6 core), barrier, convert+ds_write, barrier.
// (512,2): 256-VGPR cap — R4/R8 spilled at implied 64/128 caps.
__global__ __launch_bounds__(512, 2) void conv_mfma_col(
    const float* __restrict__ feat, const int* __restrict__ index,
    const float* __restrict__ bias, const short8* __restrict__ wpack,
    float* __restrict__ out) {
  __shared__ short smem[100 * 288];   // 57600 B, single buffer

  const int tid = threadIdx.x;
  const int lane = tid & 63;
  const int wid = tid >> 6;

  // XCD-aware bijective swizzle (1152 % 8 == 0, chunk 144); yt fastest.
  const int d = blockIdx.x;
  int L = (d & 7) * 144 + (d >> 3);
  const int yt = L % 12;  L /= 12;
  const int xt = L % 12;  L /= 12;
  const int zc = L & 1;
  const int b  = L >> 1;
  const int x0 = xt * 8, y0 = yt * 8, zc0 = zc * 48;

  // B fragments resident (56 VGPRs).
  short8 bw[14];
#pragma unroll
  for (int t = 0; t < 14; ++t) bw[t] = wpack[t * 64 + lane];

  // ---- held staging state: 4 granule-pairs (64B each) + ok flags ----
  float4 sq[4][4];
  int sok[4];

  auto stage_load = [&](int z0) {
#pragma unroll
    for (int k = 0; k < 4; ++k) {
      const int i = tid + k * 512;
      const int col = i / 18;
      const int zp  = i - col * 18;
      const int colx = col / 10, coly = col - colx * 10;
      const int gx = x0 + colx - 1, gy = y0 + coly - 1, gz = z0 + zp - 1;
      const bool ok = (i < 1800) & ((unsigned)gx < (unsigned)DSZ) &
                      ((unsigned)gy < (unsigned)DSZ) &
                      ((unsigned)gz < (unsigned)DSZ);
      sok[k] = ok;
      if (ok) {
        const float4* p = reinterpret_cast<const float4*>(
            feat + (long)(((b * DSZ + gx) * DSZ + gy) * DSZ + gz) * CIN);
        sq[k][0] = p[0];
        sq[k][1] = p[1];
        sq[k][2] = p[2];
        sq[k][3] = p[3];
      }
    }
  };

  auto stage_write = [&]() {
#pragma unroll
    for (int k = 0; k < 4; ++k) {
      const int i = tid + k * 512;
      if (i < 1800) {
        const int col = i / 18;
        const int zp  = i - col * 18;
        unsigned m0 = __builtin_amdgcn_perm(__float_as_uint(sq[k][0].y), __float_as_uint(sq[k][0].x), 0x07060302u);
        unsigned m1 = __builtin_amdgcn_perm(__float_as_uint(sq[k][0].w), __float_as_uint(sq[k][0].z), 0x07060302u);
        unsigned m2 = __builtin_amdgcn_perm(__float_as_uint(sq[k][1].y), __float_as_uint(sq[k][1].x), 0x07060302u);
        unsigned m3 = __builtin_amdgcn_perm(__float_as_uint(sq[k][1].w), __float_as_uint(sq[k][1].z), 0x07060302u);
        unsigned m4 = __builtin_amdgcn_perm(__float_as_uint(sq[k][2].y), __float_as_uint(sq[k][2].x), 0x07060302u);
        unsigned m5 = __builtin_amdgcn_perm(__float_as_uint(sq[k][2].w), __float_as_uint(sq[k][2].z), 0x07060302u);
        unsigned m6 = __builtin_amdgcn_perm(__float_as_uint(sq[k][3].y), __float_as_uint(sq[k][3].x), 0x07060302u);
        unsigned m7 = __builtin_amdgcn_perm(__float_as_uint(sq[k][3].w), __float_as_uint(sq[k][3].z), 0x07060302u);
        if (!sok[k]) { m0 = m1 = m2 = m3 = m4 = m5 = m6 = m7 = 0u; }
        const int byte0 = (col * 576 + zp * 32) ^ ((zp & 4) << 2);
        *reinterpret_cast<int4*>((char*)smem + byte0)        = make_int4(m0, m1, m2, m3);
        *reinterpret_cast<int4*>((char*)smem + (byte0 ^ 16)) = make_int4(m4, m5, m6, m7);
      }
    }
  };

  // ---- per-lane fragment addresses (R6-validated) ----
  const int cx = wid;
  const int tp = lane >> 5;
  int pre[3];
#pragma unroll
  for (int dz = 0; dz < 3; ++dz) {
    const int zp = (lane & 15) + dz;
    pre[dz] = (zp * 32 + (lane & 16)) ^ ((zp & 4) << 2);
  }
  int laddr[14];
#pragma unroll
  for (int t = 0; t < 14; ++t) {
    const int tapA = 2 * t;
    const int tapB = (2 * t + 1 <= 26) ? (2 * t + 1) : 26;  // t13: B-weights 0
    const int aA = ((cx + tapA / 9) * 10 + (tapA / 3) % 3) * 576 + pre[tapA % 3];
    const int aB = ((cx + tapB / 9) * 10 + (tapB / 3) % 3) * 576 + pre[tapB % 3];
    laddr[t] = tp ? aB : aA;
  }

  const int fq = lane & 15, hq = lane >> 4;
  const float bf = bias[fq];
  const char* smb = (const char*)smem;
  const int vcol = ((b * DSZ + (x0 + cx)) * DSZ + y0) * DSZ + hq * 4;  // + cy*96 + z0

  int4 iv[8];  // epilogue masks for the current slab, loaded issue-early

  auto load_iv = [&](int z0) {
#pragma unroll
    for (int cy = 0; cy < 8; ++cy)
      iv[cy] = *reinterpret_cast<const int4*>(index + vcol + cy * DSZ + z0);
  };

  auto compute_main = [&](int z0) {
#pragma unroll 2
    for (int cy = 0; cy < 8; ++cy) {
      f32x4 acc0 = {0.f, 0.f, 0.f, 0.f};
      f32x4 acc1 = {0.f, 0.f, 0.f, 0.f};
#pragma unroll
      for (int t = 0; t < 14; ++t) {
        I4S8 u;
        u.i = *reinterpret_cast<const int4*>(smb + laddr[t] + cy * 576);
        if (t & 1)
          acc1 = __builtin_amdgcn_mfma_f32_16x16x32_bf16(u.s, bw[t], acc1, 0, 0, 0);
        else
          acc0 = __builtin_amdgcn_mfma_f32_16x16x32_bf16(u.s, bw[t], acc0, 0, 0, 0);
      }
      float* op = out + (long)(vcol + cy * DSZ + z0) * NF + fq;
      op[0 * NF] = iv[cy].x ? (acc0[0] + acc1[0] + bf) : 0.0f;
      op[1 * NF] = iv[cy].y ? (acc0[1] + acc1[1] + bf) : 0.0f;
      op[2 * NF] = iv[cy].z ? (acc0[2] + acc1[2] + bf) : 0.0f;
      op[3 * NF] = iv[cy].w ? (acc0[3] + acc1[3] + bf) : 0.0f;
    }
  };

  // ---- column pipeline: 3 slabs, stage s+1 in flight during compute s ----
  stage_load(zc0);
  stage_write();
  __syncthreads();

  load_iv(zc0);                 // issued BEFORE next stage -> counted waits
  stage_load(zc0 + 16);
  compute_main(zc0);
  __syncthreads();
  stage_write();
  __syncthreads();

  load_iv(zc0 + 16);
  stage_load(zc0 + 32);
  compute_main(zc0 + 16);
  __syncthreads();
  stage_write();
  __syncthreads();

  load_iv(zc0 + 32);
  compute_main(zc0 + 32);
}

// ---------------- fallback (tiny ws): round-1 f32 kernel ----------------
__global__ __launch_bounds__(256) void sparse_conv_f32(
    const float* __restrict__ feat, const int* __restrict__ index,
    const float* __restrict__ w, const float* __restrict__ bias,
    float* __restrict__ out) {
  const int v = blockIdx.x * 256 + threadIdx.x;
  const int z = v % DSZ;
  int t = v / DSZ;
  const int y = t % DSZ; t /= DSZ;
  const int x = t % DSZ;
  const int bb = t / DSZ;
  float acc[NF];
#pragma unroll
  for (int f = 0; f < NF; ++f) acc[f] = bias[f];
  const bool active = (index[v] != 0);
#pragma unroll 1
  for (int kx = -1; kx <= 1; ++kx) {
    const int xx = x + kx;
    const bool okx = ((unsigned)xx < (unsigned)DSZ);
#pragma unroll 1
    for (int ky = -1; ky <= 1; ++ky) {
      const int yy = y + ky;
      const bool oky = okx && ((unsigned)yy < (unsigned)DSZ);
#pragma unroll 1
      for (int kz = -1; kz <= 1; ++kz) {
        const int zz = z + kz;
        const bool ok = oky && ((unsigned)zz < (unsigned)DSZ);
        const long long off = ((((long long)bb * DSZ + xx) * DSZ + yy) * DSZ + zz) * CIN;
        float4 q0, q1, q2, q3;
        if (ok) {
          const float4* fp = reinterpret_cast<const float4*>(feat + off);
          q0 = fp[0]; q1 = fp[1]; q2 = fp[2]; q3 = fp[3];
        } else {
          q0 = q1 = q2 = q3 = make_float4(0.f, 0.f, 0.f, 0.f);
        }
        const float fv[CIN] = {q0.x, q0.y, q0.z, q0.w, q1.x, q1.y, q1.z, q1.w,
                               q2.x, q2.y, q2.z, q2.w, q3.x, q3.y, q3.z, q3.w};
        const float* wr = w + ((((kx + 1) * 3 + (ky + 1)) * 3 + (kz + 1)) * CIN) * NF;
#pragma unroll
        for (int ci = 0; ci < CIN; ++ci) {
          const float fvv = fv[ci];
#pragma unroll
          for (int f = 0; f < NF; ++f) acc[f] = fmaf(fvv, wr[ci * NF + f], acc[f]);
        }
      }
    }
  }
  float4* op = reinterpret_cast<float4*>(out + (long long)v * NF);
  if (active) {
    op[0] = make_float4(acc[0], acc[1], acc[2], acc[3]);
    op[1] = make_float4(acc[4], acc[5], acc[6], acc[7]);
    op[2] = make_float4(acc[8], acc[9], acc[10], acc[11]);
    op[3] = make_float4(acc[12], acc[13], acc[14], acc[15]);
  } else {
    const float4 z4 = make_float4(0.f, 0.f, 0.f, 0.f);
    op[0] = z4; op[1] = z4; op[2] = z4; op[3] = z4;
  }
}

extern "C" void kernel_launch(void* const* d_in, const int* in_sizes, int n_in,
                              void* d_out, int out_size, void* d_ws, size_t ws_size,
                              hipStream_t stream) {
  const float* feat  = (const float*)d_in[0];
  const int*   index = (const int*)d_in[1];
  const float* w     = (const float*)d_in[2];
  const float* bias  = (const float*)d_in[3];
  float*       out   = (float*)d_out;

  const int nvox = in_sizes[1];  // 4*96*96*96

  if (ws_size < 14 * 64 * 8 * sizeof(short)) {
    sparse_conv_f32<<<nvox / 256, 256, 0, stream>>>(feat, index, w, bias, out);
    return;
  }

  short* wpack = (short*)d_ws;
  pack_w<<<1, 14 * 64, 0, stream>>>(w, wpack);

  const int blocks = 4 * 2 * 12 * 12;  // 1152 half-columns
  conv_mfma_col<<<blocks, 512, 0, stream>>>(feat, index, bias,
                                            (const short8*)wpack, out);
}

// Round 11
// 143.954 us; speedup vs baseline: 1.5437x; 1.5437x over previous
//
#include <hip/hip_runtime.h>

#define DSZ 96
#define CIN 16
#define NF  16
#define BUFB 28800   // bytes per LDS buffer (50 cols * 576 B); bits 0-5 zero

typedef __attribute__((ext_vector_type(8))) short short8;   // 8 bf16
typedef __attribute__((ext_vector_type(4))) float f32x4;    // MFMA C/D

union I4S8 { int4 i; short8 s; };

// ---------------- prepass: pack w into B-fragment layout (R6-validated) ----
// k = ((l>>4)&1)*8 + j ; tap = 2t + (l>>5) ; tap 27 -> zeros.
__global__ void pack_w(const float* __restrict__ w, short* __restrict__ wpack) {
  const int t = threadIdx.x >> 6;   // 0..13
  const int l = threadIdx.x & 63;
  const int tap = 2 * t + (l >> 5);
  const int cib = ((l >> 4) & 1) * 8;
  const int f = l & 15;
  short v[8];
#pragma unroll
  for (int j = 0; j < 8; ++j) {
    float x = (tap <= 26) ? w[(tap * 16 + cib + j) * 16 + f] : 0.0f;
    unsigned u = __float_as_uint(x);
    u = (u + 0x7FFFu + ((u >> 16) & 1u)) >> 16;  // RNE to bf16
    v[j] = (short)u;
  }
  short8 s;
#pragma unroll
  for (int j = 0; j < 8; ++j) s[j] = v[j];
  reinterpret_cast<short8*>(wpack)[t * 64 + l] = s;
}

// ---------------- main: z-persistent, LDS double-buffered MFMA conv ----------
// Block = 512 threads (8 waves) owns an 8x3 xy tile over all 96 z (6 tiles).
// Per z-tile: stage(t+1) into buf^1 (self-contained: load->perm->ds_write,
// NOTHING held across compute — R4/R8/R10 all spilled that), then compute(t)
// from buf, then ONE barrier. 5/6 of stages overlap compute (T3 minimal).
__global__ __launch_bounds__(512, 2) void conv_mfma_zp(
    const float* __restrict__ feat, const int* __restrict__ index,
    const float* __restrict__ bias, const short8* __restrict__ wpack,
    float* __restrict__ out) {
  __shared__ short smem[2 * 50 * 288];   // 57600 B = 2 buffers

  const int tid = threadIdx.x;
  const int lane = tid & 63;
  const int wid = tid >> 6;

  // XCD-aware bijective swizzle (1536 % 8 == 0, chunk 192); yt fastest.
  const int d = blockIdx.x;
  int L = (d & 7) * 192 + (d >> 3);
  const int yt = L % 32;  L /= 32;
  const int xt = L % 12;
  const int b  = L / 12;
  const int x0 = xt * 8, y0 = yt * 3;

  // B fragments resident (56 VGPRs).
  short8 bw[14];
#pragma unroll
  for (int t = 0; t < 14; ++t) bw[t] = wpack[t * 64 + lane];

  // ---- stage: 50 cols x 18 z-lines into buf at bufoff (f32 -> bf16) ----
  auto stage = [&](int z0, int bufoff) {
#pragma unroll
    for (int k = 0; k < 2; ++k) {
      const int i = tid + k * 512;
      if (i < 900) {
        const int col = i / 18;
        const int zp  = i - col * 18;
        const int colx = col / 5, coly = col - colx * 5;
        const int gx = x0 + colx - 1, gy = y0 + coly - 1, gz = z0 + zp - 1;
        const bool ok = ((unsigned)gx < (unsigned)DSZ) &
                        ((unsigned)gy < (unsigned)DSZ) &
                        ((unsigned)gz < (unsigned)DSZ);
        const long off = ok ? ((long)(((b * DSZ + gx) * DSZ + gy) * DSZ + gz) * CIN) : 0;
        const float4* p = reinterpret_cast<const float4*>(feat + off);
        float4 q0 = p[0], q1 = p[1], q2 = p[2], q3 = p[3];
        unsigned m0 = __builtin_amdgcn_perm(__float_as_uint(q0.y), __float_as_uint(q0.x), 0x07060302u);
        unsigned m1 = __builtin_amdgcn_perm(__float_as_uint(q0.w), __float_as_uint(q0.z), 0x07060302u);
        unsigned m2 = __builtin_amdgcn_perm(__float_as_uint(q1.y), __float_as_uint(q1.x), 0x07060302u);
        unsigned m3 = __builtin_amdgcn_perm(__float_as_uint(q1.w), __float_as_uint(q1.z), 0x07060302u);
        unsigned m4 = __builtin_amdgcn_perm(__float_as_uint(q2.y), __float_as_uint(q2.x), 0x07060302u);
        unsigned m5 = __builtin_amdgcn_perm(__float_as_uint(q2.w), __float_as_uint(q2.z), 0x07060302u);
        unsigned m6 = __builtin_amdgcn_perm(__float_as_uint(q3.y), __float_as_uint(q3.x), 0x07060302u);
        unsigned m7 = __builtin_amdgcn_perm(__float_as_uint(q3.w), __float_as_uint(q3.z), 0x07060302u);
        if (!ok) { m0 = m1 = m2 = m3 = m4 = m5 = m6 = m7 = 0u; }
        // XOR applied last within the logical offset; granule select is ^16
        const int byte0 = bufoff + ((col * 576 + zp * 32) ^ ((zp & 4) << 2));
        *reinterpret_cast<int4*>((char*)smem + byte0)        = make_int4(m0, m1, m2, m3);
        *reinterpret_cast<int4*>((char*)smem + (byte0 ^ 16)) = make_int4(m4, m5, m6, m7);
      }
    }
  };

  // ---- per-lane fragment addresses (R6-validated fold; 5-wide columns) ----
  const int cx = wid;
  const int tp = lane >> 5;
  int pre[3];
#pragma unroll
  for (int dz = 0; dz < 3; ++dz) {
    const int zp = (lane & 15) + dz;
    pre[dz] = (zp * 32 + (lane & 16)) ^ ((zp & 4) << 2);
  }
  int laddr[14];
#pragma unroll
  for (int t = 0; t < 14; ++t) {
    const int tapA = 2 * t;
    const int tapB = (2 * t + 1 <= 26) ? (2 * t + 1) : 26;  // t13: B-weights 0
    const int aA = ((cx + tapA / 9) * 5 + (tapA / 3) % 3) * 576 + pre[tapA % 3];
    const int aB = ((cx + tapB / 9) * 5 + (tapB / 3) % 3) * 576 + pre[tapB % 3];
    laddr[t] = tp ? aB : aA;
  }

  const int fq = lane & 15, hq = lane >> 4;
  const float bf = bias[fq];
  const char* smb = (const char*)smem;
  const int rowbase = (b * DSZ + (x0 + cx)) * DSZ + y0;  // + cy rows

  auto compute = [&](int z0, int bufoff) {
#pragma unroll
    for (int cy = 0; cy < 3; ++cy) {
      f32x4 acc0 = {0.f, 0.f, 0.f, 0.f};
      f32x4 acc1 = {0.f, 0.f, 0.f, 0.f};
#pragma unroll
      for (int t = 0; t < 14; ++t) {
        I4S8 u;
        u.i = *reinterpret_cast<const int4*>(smb + bufoff + laddr[t] + cy * 576);
        if (t & 1)
          acc1 = __builtin_amdgcn_mfma_f32_16x16x32_bf16(u.s, bw[t], acc1, 0, 0, 0);
        else
          acc0 = __builtin_amdgcn_mfma_f32_16x16x32_bf16(u.s, bw[t], acc0, 0, 0, 0);
      }
      const int vb = (rowbase + cy) * DSZ + z0 + hq * 4;
      const int4 iv = *reinterpret_cast<const int4*>(index + vb);
      float* op = out + (long)vb * NF + fq;
      op[0 * NF] = iv.x ? (acc0[0] + acc1[0] + bf) : 0.0f;
      op[1 * NF] = iv.y ? (acc0[1] + acc1[1] + bf) : 0.0f;
      op[2 * NF] = iv.z ? (acc0[2] + acc1[2] + bf) : 0.0f;
      op[3 * NF] = iv.w ? (acc0[3] + acc1[3] + bf) : 0.0f;
    }
  };

  // ---- z pipeline: stage(t+1) overlaps compute(t); one barrier per tile ----
  stage(0, 0);
  __syncthreads();
#pragma unroll
  for (int zt = 0; zt < 6; ++zt) {
    if (zt < 5) stage((zt + 1) * 16, ((zt + 1) & 1) * BUFB);
    compute(zt * 16, (zt & 1) * BUFB);
    __syncthreads();
  }
}

// ---------------- fallback (tiny ws): round-1 f32 kernel ----------------
__global__ __launch_bounds__(256) void sparse_conv_f32(
    const float* __restrict__ feat, const int* __restrict__ index,
    const float* __restrict__ w, const float* __restrict__ bias,
    float* __restrict__ out) {
  const int v = blockIdx.x * 256 + threadIdx.x;
  const int z = v % DSZ;
  int t = v / DSZ;
  const int y = t % DSZ; t /= DSZ;
  const int x = t % DSZ;
  const int bb = t / DSZ;
  float acc[NF];
#pragma unroll
  for (int f = 0; f < NF; ++f) acc[f] = bias[f];
  const bool active = (index[v] != 0);
#pragma unroll 1
  for (int kx = -1; kx <= 1; ++kx) {
    const int xx = x + kx;
    const bool okx = ((unsigned)xx < (unsigned)DSZ);
#pragma unroll 1
    for (int ky = -1; ky <= 1; ++ky) {
      const int yy = y + ky;
      const bool oky = okx && ((unsigned)yy < (unsigned)DSZ);
#pragma unroll 1
      for (int kz = -1; kz <= 1; ++kz) {
        const int zz = z + kz;
        const bool ok = oky && ((unsigned)zz < (unsigned)DSZ);
        const long long off = ((((long long)bb * DSZ + xx) * DSZ + yy) * DSZ + zz) * CIN;
        float4 q0, q1, q2, q3;
        if (ok) {
          const float4* fp = reinterpret_cast<const float4*>(feat + off);
          q0 = fp[0]; q1 = fp[1]; q2 = fp[2]; q3 = fp[3];
        } else {
          q0 = q1 = q2 = q3 = make_float4(0.f, 0.f, 0.f, 0.f);
        }
        const float fv[CIN] = {q0.x, q0.y, q0.z, q0.w, q1.x, q1.y, q1.z, q1.w,
                               q2.x, q2.y, q2.z, q2.w, q3.x, q3.y, q3.z, q3.w};
        const float* wr = w + ((((kx + 1) * 3 + (ky + 1)) * 3 + (kz + 1)) * CIN) * NF;
#pragma unroll
        for (int ci = 0; ci < CIN; ++ci) {
          const float fvv = fv[ci];
#pragma unroll
          for (int f = 0; f < NF; ++f) acc[f] = fmaf(fvv, wr[ci * NF + f], acc[f]);
        }
      }
    }
  }
  float4* op = reinterpret_cast<float4*>(out + (long long)v * NF);
  if (active) {
    op[0] = make_float4(acc[0], acc[1], acc[2], acc[3]);
    op[1] = make_float4(acc[4], acc[5], acc[6], acc[7]);
    op[2] = make_float4(acc[8], acc[9], acc[10], acc[11]);
    op[3] = make_float4(acc[12], acc[13], acc[14], acc[15]);
  } else {
    const float4 z4 = make_float4(0.f, 0.f, 0.f, 0.f);
    op[0] = z4; op[1] = z4; op[2] = z4; op[3] = z4;
  }
}

extern "C" void kernel_launch(void* const* d_in, const int* in_sizes, int n_in,
                              void* d_out, int out_size, void* d_ws, size_t ws_size,
                              hipStream_t stream) {
  const float* feat  = (const float*)d_in[0];
  const int*   index = (const int*)d_in[1];
  const float* w     = (const float*)d_in[2];
  const float* bias  = (const float*)d_in[3];
  float*       out   = (float*)d_out;

  const int nvox = in_sizes[1];  // 4*96*96*96

  if (ws_size < 14 * 64 * 8 * sizeof(short)) {
    sparse_conv_f32<<<nvox / 256, 256, 0, stream>>>(feat, index, w, bias, out);
    return;
  }

  short* wpack = (short*)d_ws;
  pack_w<<<1, 14 * 64, 0, stream>>>(w, wpack);

  const int blocks = 4 * 12 * 32;  // 1536 = 6 * 256 CUs — zero tail
  conv_mfma_zp<<<blocks, 512, 0, stream>>>(feat, index, bias,
                                           (const short8*)wpack, out);
}